// Round 2
// baseline (2278.832 us; speedup 1.0000x reference)
//
#include <hip/hip_runtime.h>
#include <hip/hip_bf16.h>
#include <hip/hip_fp16.h>

// BRNN: K0a/K0b fp32->fp16 convert+pad, K1 MFMA fp16 GEMM -> gate preacts G,
// K2 recurrence (24 blocks = lane x dir, weights VGPR-resident 128 u32/thread),
// K3 per-doc epilogue.
// ws: [0,66453504) x_h (aliased by H after K1) | [66453504) W_h | [88604672) G. total 113,770,496 B.

typedef _Float16 h8 __attribute__((ext_vector_type(8)));
typedef _Float16 h2 __attribute__((ext_vector_type(2)));
typedef float f4 __attribute__((ext_vector_type(4)));

#define SEQ 512
#define NL 12
#define KIN 5400
#define KP 5408
#define NG 2048

__device__ __forceinline__ unsigned int pk2(float a, float b){
  h2 v; v[0] = (_Float16)a; v[1] = (_Float16)b;
  return __builtin_bit_cast(unsigned int, v);
}
__device__ __forceinline__ float dot2u(unsigned int h, unsigned int w, float acc){
  return __builtin_amdgcn_fdot2(__builtin_bit_cast(h2, h), __builtin_bit_cast(h2, w), acc, false);
}
__device__ __forceinline__ float sigm(float x){ return 1.f/(1.f + __expf(-x)); }
__device__ __forceinline__ float tanhx(float x){ return 1.f - 2.f/(__expf(2.f*x) + 1.f); }
__device__ __forceinline__ float dppadd_b1(float v){
  int x = __builtin_amdgcn_mov_dpp(__builtin_bit_cast(int, v), 0xB1, 0xF, 0xF, true);
  return v + __builtin_bit_cast(float, x);
}
__device__ __forceinline__ float dppadd_4e(float v){
  int x = __builtin_amdgcn_mov_dpp(__builtin_bit_cast(int, v), 0x4E, 0xF, 0xF, true);
  return v + __builtin_bit_cast(float, x);
}

// ---------------- K0a: x (6144x5400 f32) -> xh (6144x5408 f16, zero pad) ----------------
__global__ void cvt_x(const float* __restrict__ x, _Float16* __restrict__ xh){
  int idx = blockIdx.x * 256 + threadIdx.x;
  int row = idx / KP, col = idx - row * KP;
  float v = (col < KIN) ? x[(size_t)row * KIN + col] : 0.f;
  xh[idx] = (_Float16)v;
}

// ---------------- K0b: [Wih_f; Wih_b] -> wh (2048x5408 f16, zero pad) ----------------
__global__ void cvt_w(const float* __restrict__ wf, const float* __restrict__ wb,
                      _Float16* __restrict__ wh){
  int idx = blockIdx.x * 256 + threadIdx.x;
  int row = idx / KP, col = idx - row * KP;
  float v = 0.f;
  if (col < KIN)
    v = (row < 1024) ? wf[(size_t)row * KIN + col] : wb[(size_t)(row - 1024) * KIN + col];
  wh[idx] = (_Float16)v;
}

// ---------------- K1: G = xh @ wh^T + bias, fp16 MFMA, 128x128 tiles ----------------
__global__ __launch_bounds__(256) void gemm_in(
    const _Float16* __restrict__ A, const _Float16* __restrict__ B, _Float16* __restrict__ G,
    const float* __restrict__ bif, const float* __restrict__ bhf,
    const float* __restrict__ bib, const float* __restrict__ bhb){
  __shared__ _Float16 As[128 * 40];
  __shared__ _Float16 Bs[128 * 40];
  int tid = threadIdx.x;
  int bm = blockIdx.x % 48, bn = blockIdx.x / 48;
  int wid = tid >> 6, ln = tid & 63;
  int wm = wid & 1, wn = wid >> 1;
  int l15 = ln & 15, q = ln >> 4;
  int i0 = tid, i1 = tid + 256;
  int r0 = i0 >> 2, c0 = i0 & 3, r1 = i1 >> 2, c1 = i1 & 3;
  const size_t a0 = (size_t)(bm*128 + r0) * KP + c0*8;
  const size_t a1 = (size_t)(bm*128 + r1) * KP + c1*8;
  const size_t b0 = (size_t)(bn*128 + r0) * KP + c0*8;
  const size_t b1 = (size_t)(bn*128 + r1) * KP + c1*8;
  f4 acc[4][4] = {};
  for (int kk = 0; kk < 169; ++kk){
    int k0 = kk * 32;
    uint4 va0 = *(const uint4*)(A + a0 + k0);
    uint4 va1 = *(const uint4*)(A + a1 + k0);
    uint4 vb0 = *(const uint4*)(B + b0 + k0);
    uint4 vb1 = *(const uint4*)(B + b1 + k0);
    __syncthreads();
    *(uint4*)(As + r0*40 + c0*8) = va0;
    *(uint4*)(As + r1*40 + c1*8) = va1;
    *(uint4*)(Bs + r0*40 + c0*8) = vb0;
    *(uint4*)(Bs + r1*40 + c1*8) = vb1;
    __syncthreads();
    h8 af[4], bfr[4];
    #pragma unroll
    for (int mt = 0; mt < 4; ++mt)
      af[mt] = *(const h8*)(As + (wm*64 + mt*16 + l15)*40 + q*8);
    #pragma unroll
    for (int nt = 0; nt < 4; ++nt)
      bfr[nt] = *(const h8*)(Bs + (wn*64 + nt*16 + l15)*40 + q*8);
    #pragma unroll
    for (int mt = 0; mt < 4; ++mt)
      #pragma unroll
      for (int nt = 0; nt < 4; ++nt)
        acc[mt][nt] = __builtin_amdgcn_mfma_f32_16x16x32_f16(af[mt], bfr[nt], acc[mt][nt], 0, 0, 0);
  }
  float bias[4];
  #pragma unroll
  for (int nt = 0; nt < 4; ++nt){
    int col = bn*128 + wn*64 + nt*16 + l15;
    bias[nt] = (col < 1024) ? (bif[col] + bhf[col]) : (bib[col-1024] + bhb[col-1024]);
  }
  #pragma unroll
  for (int mt = 0; mt < 4; ++mt)
    #pragma unroll
    for (int nt = 0; nt < 4; ++nt)
      #pragma unroll
      for (int r = 0; r < 4; ++r){
        int row = bm*128 + wm*64 + mt*16 + q*4 + r;
        int col = bn*128 + wn*64 + nt*16 + l15;
        G[(size_t)row * NG + col] = (_Float16)(acc[mt][nt][r] + bias[nt]);
      }
}

// ---------------- K2: recurrence, weights VGPR-resident ----------------
// 24 blocks = (dir,lane), 1024 threads. Thread t: e = t>>2 (h-dim), q = t&3 (K-quarter).
// Holds K-quarter q of gate rows {e, 256+e, 512+e, 768+e}: 4 x 8 uint4 = 128 VGPRs.
// Per step: 8 ds_read_b128 (h-quarter, pad 144 B -> conflict-free), 128 dot2,
// DPP quad-reduce (0xB1,0x4E) -> all 4 gates in-thread; c/h redundant in quad;
// 1 barrier/step via double-buffered h.
__global__ __launch_bounds__(1024, 4) void lstm_rec(
    const float* __restrict__ Whhf, const float* __restrict__ Whhb,
    const _Float16* __restrict__ G, float* __restrict__ Hout){
  __shared__ _Float16 hlds[2][4][72];   // 1152 B
  int b = blockIdx.x;
  int dir = b / 12, lane = b - dir * 12;
  int t = threadIdx.x;
  int e = t >> 2, q = t & 3;
  const float* Whh = dir ? Whhb : Whhf;

  uint4 wreg[4][8];
  #pragma unroll
  for (int g = 0; g < 4; ++g){
    const float* wr = Whh + (size_t)(g*256 + e) * 256 + q*64;
    #pragma unroll
    for (int i = 0; i < 8; ++i){
      f4 v0 = *(const f4*)(wr + i*8);
      f4 v1 = *(const f4*)(wr + i*8 + 4);
      wreg[g][i].x = pk2(v0[0], v0[1]);
      wreg[g][i].y = pk2(v0[2], v0[3]);
      wreg[g][i].z = pk2(v1[0], v1[1]);
      wreg[g][i].w = pk2(v1[2], v1[3]);
    }
  }
  if (t < 288) ((unsigned int*)hlds)[t] = 0u;

  const uint4* hq0 = (const uint4*)&hlds[0][q][0];
  const uint4* hq1 = (const uint4*)&hlds[1][q][0];
  int s0 = dir ? (SEQ - 1) : 0;
  long sstep = dir ? -(long)(NL*NG) : (long)(NL*NG);
  long hstep = dir ? -(long)(NL*512) : (long)(NL*512);
  const _Float16* gp = G + (size_t)(s0*NL + lane) * NG + dir * 1024 + e;
  float* hp = Hout + (size_t)(s0*NL + lane) * 512 + dir * 256 + e;
  float cst = 0.f;
  __syncthreads();

  for (int it = 0; it < SEQ; ++it){
    float ga = (float)gp[0];
    float gf = (float)gp[256];
    float gg = (float)gp[512];
    float go = (float)gp[768];
    const uint4* hp16 = (it & 1) ? hq1 : hq0;
    float a0 = 0.f, a1 = 0.f, a2 = 0.f, a3 = 0.f;
    #pragma unroll
    for (int i = 0; i < 8; ++i){
      uint4 hv = hp16[i];
      a0 = dot2u(hv.x, wreg[0][i].x, a0); a0 = dot2u(hv.y, wreg[0][i].y, a0);
      a0 = dot2u(hv.z, wreg[0][i].z, a0); a0 = dot2u(hv.w, wreg[0][i].w, a0);
      a1 = dot2u(hv.x, wreg[1][i].x, a1); a1 = dot2u(hv.y, wreg[1][i].y, a1);
      a1 = dot2u(hv.z, wreg[1][i].z, a1); a1 = dot2u(hv.w, wreg[1][i].w, a1);
      a2 = dot2u(hv.x, wreg[2][i].x, a2); a2 = dot2u(hv.y, wreg[2][i].y, a2);
      a2 = dot2u(hv.z, wreg[2][i].z, a2); a2 = dot2u(hv.w, wreg[2][i].w, a2);
      a3 = dot2u(hv.x, wreg[3][i].x, a3); a3 = dot2u(hv.y, wreg[3][i].y, a3);
      a3 = dot2u(hv.z, wreg[3][i].z, a3); a3 = dot2u(hv.w, wreg[3][i].w, a3);
    }
    a0 = dppadd_4e(dppadd_b1(a0));
    a1 = dppadd_4e(dppadd_b1(a1));
    a2 = dppadd_4e(dppadd_b1(a2));
    a3 = dppadd_4e(dppadd_b1(a3));
    float pi = a0 + ga, pf = a1 + gf, pg = a2 + gg, po = a3 + go;
    cst = sigm(pf)*cst + sigm(pi)*tanhx(pg);
    float hv = sigm(po)*tanhx(cst);
    hlds[(it & 1) ^ 1][e >> 6][e & 63] = (_Float16)hv;   // quad-redundant same-value write
    if (q == 0) *hp = hv;
    gp += sstep; hp += hstep;
    __syncthreads();
  }
}

// ---------------- K3: per-doc epilogue ----------------
__global__ __launch_bounds__(256) void epilogue(
    const float* __restrict__ H, const float* __restrict__ encW, const float* __restrict__ encB,
    const float* __restrict__ wfcW, const float* __restrict__ wfcB,
    const float* __restrict__ fcW, const float* __restrict__ fcB, float* __restrict__ out){
  __shared__ float B0[12][516];
  __shared__ float B1[12][516];
  __shared__ float encl[12][52];
  __shared__ float part[12][16];
  __shared__ float av[12], bv[12], nrm[12], simv[12], rsv[12], docv[12];
  __shared__ float Wm[12][12];
  __shared__ int corei;
  int d = blockIdx.x, t = threadIdx.x;
  const float* Hd = H + (size_t)d * NL * 512;
  for (int idx = t; idx < NL * 128; idx += 256){
    int i = idx >> 7, h4 = (idx & 127) * 4;
    *(f4*)(&B0[i][h4]) = *(const f4*)(Hd + i*512 + h4);
  }
  __syncthreads();
  for (int idx = t; idx < 600; idx += 256){
    int i = idx % 12, e = idx / 12;
    float s = encB[e];
    const float* w = encW + e * 512;
    for (int h = 0; h < 512; ++h) s += B0[i][h] * w[h];
    encl[i][e] = (s >= 0.f) ? s : 0.01f * s;
  }
  __syncthreads();
  if (t < 12){
    float sa = 0.f, sb = 0.f;
    for (int e = 0; e < 50; ++e){ sa += encl[t][e]*wfcW[e]; sb += encl[t][e]*wfcW[50 + e]; }
    av[t] = sa; bv[t] = sb;
  }
  __syncthreads();
  if (t < 192){
    int i = t >> 4, sl = t & 15;
    float s = 0.f;
    for (int h = sl*32; h < sl*32 + 32; ++h){ float v = B0[i][h]; s += v*v; }
    part[i][sl] = s;
  }
  if (t == 192){
    float wbv = wfcB[0];
    float best = -1e30f; int bi = 0;
    for (int i = 0; i < 12; ++i){
      float rs = 0.f;
      for (int j = 0; j < 12; ++j) if (j != i) rs += av[i] + bv[j] + wbv;
      if (rs > best){ best = rs; bi = i; }
    }
    corei = bi;
  }
  __syncthreads();
  if (t < 12){
    float s = 0.f; for (int l = 0; l < 16; ++l) s += part[t][l];
    nrm[t] = sqrtf(s) + 1e-12f;
  }
  __syncthreads();
  if (t < 192){
    int i = t >> 4, sl = t & 15, cc = corei;
    float s = 0.f;
    for (int h = sl*32; h < sl*32 + 32; ++h) s += B0[i][h] * B0[cc][h];
    part[i][sl] = s;
  }
  __syncthreads();
  if (t < 12){
    float s = 0.f; for (int l = 0; l < 16; ++l) s += part[t][l];
    simv[t] = s / (nrm[t] * nrm[corei]);
  }
  __syncthreads();
  if (t < 12){
    int rk = 0; float st = simv[t];
    for (int j = 0; j < 12; ++j){
      float sj = simv[j];
      rk += (sj > st) || (sj == st && j < t);
    }
    rsv[t] = 1.f - (float)rk / 12.f;
  }
  __syncthreads();
  if (t < 144){
    int i = t / 12, j = t - (t / 12) * 12;
    Wm[i][j] = (i == j) ? 0.f : (av[i] + bv[j] + wfcB[0]) * rsv[i];
  }
  __syncthreads();
  for (int h = t; h < 512; h += 256){
    float e[12];
    #pragma unroll
    for (int j = 0; j < 12; ++j) e[j] = B0[j][h];
    #pragma unroll
    for (int i = 0; i < 12; ++i){
      float s = e[i];
      #pragma unroll
      for (int j = 0; j < 12; ++j) s += Wm[i][j] * e[j];
      B1[i][h] = s;
    }
  }
  __syncthreads();
  for (int h = t; h < 512; h += 256){
    float e[12];
    #pragma unroll
    for (int j = 0; j < 12; ++j) e[j] = B1[j][h];
    #pragma unroll
    for (int i = 0; i < 12; ++i){
      float s = e[i];
      #pragma unroll
      for (int j = 0; j < 12; ++j) s += Wm[i][j] * e[j];
      B0[i][h] = s;
    }
  }
  __syncthreads();
  if (t < 192){
    int i = t >> 4, sl = t & 15;
    float s = 0.f;
    for (int h = sl*32; h < sl*32 + 32; ++h) s += B0[i][h];
    part[i][sl] = s;
  }
  __syncthreads();
  if (t < 12){
    float s = 0.f; for (int l = 0; l < 16; ++l) s += part[t][l];
    docv[t] = s / 512.f;
  }
  __syncthreads();
  if (t < 2){
    float s = fcB[t];
    for (int i = 0; i < 12; ++i) s += docv[i] * fcW[t*12 + i];
    out[d*2 + t] = s;
  }
}

extern "C" void kernel_launch(void* const* d_in, const int* in_sizes, int n_in,
                              void* d_out, int out_size, void* d_ws, size_t ws_size,
                              hipStream_t stream){
  const float* x    = (const float*)d_in[0];
  const float* Wihf = (const float*)d_in[1];
  const float* Whhf = (const float*)d_in[2];
  const float* bihf = (const float*)d_in[3];
  const float* bhhf = (const float*)d_in[4];
  const float* Wihb = (const float*)d_in[5];
  const float* Whhb = (const float*)d_in[6];
  const float* bihb = (const float*)d_in[7];
  const float* bhhb = (const float*)d_in[8];
  const float* encW = (const float*)d_in[9];
  const float* encB = (const float*)d_in[10];
  const float* wfcW = (const float*)d_in[11];
  const float* wfcB = (const float*)d_in[12];
  const float* fcW  = (const float*)d_in[13];
  const float* fcB  = (const float*)d_in[14];
  float* out = (float*)d_out;
  char* ws = (char*)d_ws;
  _Float16* xh = (_Float16*)(ws);
  _Float16* wh = (_Float16*)(ws + 66453504);
  _Float16* G  = (_Float16*)(ws + 88604672);
  float* H = (float*)(ws);   // aliases dead xh after K1

  cvt_x<<<129792, 256, 0, stream>>>(x, xh);
  cvt_w<<<43264, 256, 0, stream>>>(Wihf, Wihb, wh);
  gemm_in<<<768, 256, 0, stream>>>(xh, wh, G, bihf, bhhf, bihb, bhhb);
  lstm_rec<<<24, 1024, 0, stream>>>(Whhf, Whhb, G, H);
  epilogue<<<512, 256, 0, stream>>>(H, encW, encB, wfcW, wfcB, fcW, fcB, out);
}

// Round 3
// 1705.576 us; speedup vs baseline: 1.3361x; 1.3361x over previous
//
#include <hip/hip_runtime.h>
#include <hip/hip_bf16.h>
#include <hip/hip_fp16.h>

// BRNN: K0a/K0b fp32->fp16 convert+pad, K1 MFMA fp16 GEMM -> gate preacts G,
// K2 recurrence: 24 blocks (lane x dir) x 512 thr; thread (d=t>>2 dim-pair, q=t&3 K-chunk)
//   holds 8 gate-rows' K-chunk: i,f,g gates (6 rows, 192 u32) in VGPR, o gate (2 rows) in LDS.
//   DPP quad-reduce over q. 1 barrier/step. VGPR target ~235 < 256 cap (8 waves = 2/SIMD).
// K3 per-doc epilogue.
// ws: [0,66453504) x_h (aliased by H after K1) | [66453504) W_h | [88604672) G. total 113,770,496 B.

typedef _Float16 h8 __attribute__((ext_vector_type(8)));
typedef _Float16 h2 __attribute__((ext_vector_type(2)));
typedef float f4 __attribute__((ext_vector_type(4)));

#define SEQ 512
#define NL 12
#define KIN 5400
#define KP 5408
#define NG 2048

__device__ __forceinline__ unsigned int pk2(float a, float b){
  h2 v; v[0] = (_Float16)a; v[1] = (_Float16)b;
  return __builtin_bit_cast(unsigned int, v);
}
__device__ __forceinline__ float dot2u(unsigned int h, unsigned int w, float acc){
  return __builtin_amdgcn_fdot2(__builtin_bit_cast(h2, h), __builtin_bit_cast(h2, w), acc, false);
}
__device__ __forceinline__ float dot4q(uint4 h, uint4 w, float acc){
  acc = dot2u(h.x, w.x, acc); acc = dot2u(h.y, w.y, acc);
  acc = dot2u(h.z, w.z, acc); acc = dot2u(h.w, w.w, acc);
  return acc;
}
__device__ __forceinline__ float sigm(float x){ return 1.f/(1.f + __expf(-x)); }
__device__ __forceinline__ float tanhx(float x){ return 1.f - 2.f/(__expf(2.f*x) + 1.f); }
__device__ __forceinline__ float dppadd_b1(float v){   // += lane^1 (quad_perm 1,0,3,2)
  int x = __builtin_amdgcn_mov_dpp(__builtin_bit_cast(int, v), 0xB1, 0xF, 0xF, true);
  return v + __builtin_bit_cast(float, x);
}
__device__ __forceinline__ float dppadd_4e(float v){   // += lane^2 (quad_perm 2,3,0,1)
  int x = __builtin_amdgcn_mov_dpp(__builtin_bit_cast(int, v), 0x4E, 0xF, 0xF, true);
  return v + __builtin_bit_cast(float, x);
}
__device__ __forceinline__ float lo16(unsigned int u){
  return (float)__builtin_bit_cast(h2, u)[0];
}
__device__ __forceinline__ float hi16(unsigned int u){
  return (float)__builtin_bit_cast(h2, u)[1];
}

// ---------------- K0a: x (6144x5400 f32) -> xh (6144x5408 f16, zero pad) ----------------
__global__ void cvt_x(const float* __restrict__ x, _Float16* __restrict__ xh){
  int idx = blockIdx.x * 256 + threadIdx.x;
  int row = idx / KP, col = idx - row * KP;
  float v = (col < KIN) ? x[(size_t)row * KIN + col] : 0.f;
  xh[idx] = (_Float16)v;
}

// ---------------- K0b: [Wih_f; Wih_b] -> wh (2048x5408 f16, zero pad) ----------------
__global__ void cvt_w(const float* __restrict__ wf, const float* __restrict__ wb,
                      _Float16* __restrict__ wh){
  int idx = blockIdx.x * 256 + threadIdx.x;
  int row = idx / KP, col = idx - row * KP;
  float v = 0.f;
  if (col < KIN)
    v = (row < 1024) ? wf[(size_t)row * KIN + col] : wb[(size_t)(row - 1024) * KIN + col];
  wh[idx] = (_Float16)v;
}

// ---------------- K1: G = xh @ wh^T + bias, fp16 MFMA, 128x128 tiles ----------------
__global__ __launch_bounds__(256) void gemm_in(
    const _Float16* __restrict__ A, const _Float16* __restrict__ B, _Float16* __restrict__ G,
    const float* __restrict__ bif, const float* __restrict__ bhf,
    const float* __restrict__ bib, const float* __restrict__ bhb){
  __shared__ _Float16 As[128 * 40];
  __shared__ _Float16 Bs[128 * 40];
  int tid = threadIdx.x;
  int bm = blockIdx.x % 48, bn = blockIdx.x / 48;
  int wid = tid >> 6, ln = tid & 63;
  int wm = wid & 1, wn = wid >> 1;
  int l15 = ln & 15, q = ln >> 4;
  int i0 = tid, i1 = tid + 256;
  int r0 = i0 >> 2, c0 = i0 & 3, r1 = i1 >> 2, c1 = i1 & 3;
  const size_t a0 = (size_t)(bm*128 + r0) * KP + c0*8;
  const size_t a1 = (size_t)(bm*128 + r1) * KP + c1*8;
  const size_t b0 = (size_t)(bn*128 + r0) * KP + c0*8;
  const size_t b1 = (size_t)(bn*128 + r1) * KP + c1*8;
  f4 acc[4][4] = {};
  for (int kk = 0; kk < 169; ++kk){
    int k0 = kk * 32;
    uint4 va0 = *(const uint4*)(A + a0 + k0);
    uint4 va1 = *(const uint4*)(A + a1 + k0);
    uint4 vb0 = *(const uint4*)(B + b0 + k0);
    uint4 vb1 = *(const uint4*)(B + b1 + k0);
    __syncthreads();
    *(uint4*)(As + r0*40 + c0*8) = va0;
    *(uint4*)(As + r1*40 + c1*8) = va1;
    *(uint4*)(Bs + r0*40 + c0*8) = vb0;
    *(uint4*)(Bs + r1*40 + c1*8) = vb1;
    __syncthreads();
    h8 af[4], bfr[4];
    #pragma unroll
    for (int mt = 0; mt < 4; ++mt)
      af[mt] = *(const h8*)(As + (wm*64 + mt*16 + l15)*40 + q*8);
    #pragma unroll
    for (int nt = 0; nt < 4; ++nt)
      bfr[nt] = *(const h8*)(Bs + (wn*64 + nt*16 + l15)*40 + q*8);
    #pragma unroll
    for (int mt = 0; mt < 4; ++mt)
      #pragma unroll
      for (int nt = 0; nt < 4; ++nt)
        acc[mt][nt] = __builtin_amdgcn_mfma_f32_16x16x32_f16(af[mt], bfr[nt], acc[mt][nt], 0, 0, 0);
  }
  float bias[4];
  #pragma unroll
  for (int nt = 0; nt < 4; ++nt){
    int col = bn*128 + wn*64 + nt*16 + l15;
    bias[nt] = (col < 1024) ? (bif[col] + bhf[col]) : (bib[col-1024] + bhb[col-1024]);
  }
  #pragma unroll
  for (int mt = 0; mt < 4; ++mt)
    #pragma unroll
    for (int nt = 0; nt < 4; ++nt)
      #pragma unroll
      for (int r = 0; r < 4; ++r){
        int row = bm*128 + wm*64 + mt*16 + q*4 + r;
        int col = bn*128 + wn*64 + nt*16 + l15;
        G[(size_t)row * NG + col] = (_Float16)(acc[mt][nt][r] + bias[nt]);
      }
}

// ---------------- K2: recurrence, hybrid VGPR+LDS weights ----------------
// Thread t: d = t>>2 (dims 2d,2d+1), q = t&3 (K-elems [64q,64q+64)).
// Rows: i/f/g gates x {2d,2d+1} in wreg[6][8] (192 u32); o gate x {2d,2d+1} in
// LDS wl[2][8][512] uint4 (128 KB, lane-consecutive -> conflict-free).
// h double-buffered as packed u32 pairs hb[2][128]. DPP xor1+xor2 reduce over q.
__global__ __launch_bounds__(512, 2) void lstm_rec(
    const float* __restrict__ Whhf, const float* __restrict__ Whhb,
    const _Float16* __restrict__ G, float* __restrict__ Hout){
  __shared__ uint4 wl[2][8][512];          // 131072 B
  __shared__ unsigned int hb[2][128];      // 1024 B
  int b = blockIdx.x;
  int dir = b / 12, lane = b - dir * 12;
  int t = threadIdx.x;
  int d = t >> 2, q = t & 3;
  const float* Whh = dir ? Whhb : Whhf;

  // Pack weights. VGPR rows: g in {0,1,2} (i,f,g), dd in {0,1} -> wreg[g*2+dd].
  uint4 wreg[6][8];
  #pragma unroll
  for (int g = 0; g < 3; ++g)
    #pragma unroll
    for (int dd = 0; dd < 2; ++dd){
      const float* wr = Whh + (size_t)(g*256 + 2*d + dd) * 256 + q*64;
      #pragma unroll
      for (int c = 0; c < 8; ++c){
        f4 v0 = *(const f4*)(wr + c*8);
        f4 v1 = *(const f4*)(wr + c*8 + 4);
        uint4 u;
        u.x = pk2(v0[0], v0[1]); u.y = pk2(v0[2], v0[3]);
        u.z = pk2(v1[0], v1[1]); u.w = pk2(v1[2], v1[3]);
        wreg[g*2 + dd][c] = u;
      }
    }
  // LDS rows: o gate (row 768 + 2d + dd)
  #pragma unroll
  for (int dd = 0; dd < 2; ++dd){
    const float* wr = Whh + (size_t)(768 + 2*d + dd) * 256 + q*64;
    #pragma unroll
    for (int c = 0; c < 8; ++c){
      f4 v0 = *(const f4*)(wr + c*8);
      f4 v1 = *(const f4*)(wr + c*8 + 4);
      uint4 u;
      u.x = pk2(v0[0], v0[1]); u.y = pk2(v0[2], v0[3]);
      u.z = pk2(v1[0], v1[1]); u.w = pk2(v1[2], v1[3]);
      wl[dd][c][t] = u;
    }
  }
  if (t < 256) ((unsigned int*)hb)[t] = 0u;

  int s0 = dir ? (SEQ - 1) : 0;
  long sstep = dir ? -(long)(NL*NG/2) : (long)(NL*NG/2);       // u32 units
  long hstep = dir ? -(long)(NL*512/2) : (long)(NL*512/2);     // float2 units
  const unsigned int* gp = (const unsigned int*)(G + (size_t)(s0*NL + lane) * NG + dir * 1024) + d;
  float2* hp = (float2*)(Hout + (size_t)(s0*NL + lane) * 512 + dir * 256) + d;
  float c0 = 0.f, c1 = 0.f;
  __syncthreads();

  for (int it = 0; it < SEQ; ++it){
    // preacts for dims 2d,2d+1, gates i,f,g,o (f16 pairs) — load early
    unsigned int gi = gp[0];
    unsigned int gf = gp[128];
    unsigned int gg = gp[256];
    unsigned int go = gp[384];
    const uint4* hq = (const uint4*)hb[it & 1] + q*8;
    float a0=0.f,a1=0.f,a2=0.f,a3=0.f,a4=0.f,a5=0.f,a6=0.f,a7=0.f;
    #pragma unroll
    for (int c = 0; c < 8; ++c){
      uint4 hv = hq[c];
      uint4 w6 = wl[0][c][t];
      uint4 w7 = wl[1][c][t];
      a0 = dot4q(hv, wreg[0][c], a0);
      a1 = dot4q(hv, wreg[1][c], a1);
      a2 = dot4q(hv, wreg[2][c], a2);
      a3 = dot4q(hv, wreg[3][c], a3);
      a4 = dot4q(hv, wreg[4][c], a4);
      a5 = dot4q(hv, wreg[5][c], a5);
      a6 = dot4q(hv, w6, a6);
      a7 = dot4q(hv, w7, a7);
    }
    a0 = dppadd_4e(dppadd_b1(a0));
    a1 = dppadd_4e(dppadd_b1(a1));
    a2 = dppadd_4e(dppadd_b1(a2));
    a3 = dppadd_4e(dppadd_b1(a3));
    a4 = dppadd_4e(dppadd_b1(a4));
    a5 = dppadd_4e(dppadd_b1(a5));
    a6 = dppadd_4e(dppadd_b1(a6));
    a7 = dppadd_4e(dppadd_b1(a7));
    // rows: a[0]=i·d0 a[1]=i·d1 a[2]=f·d0 a[3]=f·d1 a[4]=g·d0 a[5]=g·d1 a[6]=o·d0 a[7]=o·d1
    float pi0 = a0 + lo16(gi), pi1 = a1 + hi16(gi);
    float pf0 = a2 + lo16(gf), pf1 = a3 + hi16(gf);
    float pg0 = a4 + lo16(gg), pg1 = a5 + hi16(gg);
    float po0 = a6 + lo16(go), po1 = a7 + hi16(go);
    c0 = sigm(pf0)*c0 + sigm(pi0)*tanhx(pg0);
    c1 = sigm(pf1)*c1 + sigm(pi1)*tanhx(pg1);
    float h0 = sigm(po0)*tanhx(c0);
    float h1 = sigm(po1)*tanhx(c1);
    if (q == 0){
      hb[(it & 1) ^ 1][d] = pk2(h0, h1);
      float2 hw; hw.x = h0; hw.y = h1;
      *hp = hw;
    }
    gp += sstep; hp += hstep;
    __syncthreads();
  }
}

// ---------------- K3: per-doc epilogue ----------------
__global__ __launch_bounds__(256) void epilogue(
    const float* __restrict__ H, const float* __restrict__ encW, const float* __restrict__ encB,
    const float* __restrict__ wfcW, const float* __restrict__ wfcB,
    const float* __restrict__ fcW, const float* __restrict__ fcB, float* __restrict__ out){
  __shared__ float B0[12][516];
  __shared__ float B1[12][516];
  __shared__ float encl[12][52];
  __shared__ float part[12][16];
  __shared__ float av[12], bv[12], nrm[12], simv[12], rsv[12], docv[12];
  __shared__ float Wm[12][12];
  __shared__ int corei;
  int d = blockIdx.x, t = threadIdx.x;
  const float* Hd = H + (size_t)d * NL * 512;
  for (int idx = t; idx < NL * 128; idx += 256){
    int i = idx >> 7, h4 = (idx & 127) * 4;
    *(f4*)(&B0[i][h4]) = *(const f4*)(Hd + i*512 + h4);
  }
  __syncthreads();
  for (int idx = t; idx < 600; idx += 256){
    int i = idx % 12, e = idx / 12;
    float s = encB[e];
    const float* w = encW + e * 512;
    for (int h = 0; h < 512; ++h) s += B0[i][h] * w[h];
    encl[i][e] = (s >= 0.f) ? s : 0.01f * s;
  }
  __syncthreads();
  if (t < 12){
    float sa = 0.f, sb = 0.f;
    for (int e = 0; e < 50; ++e){ sa += encl[t][e]*wfcW[e]; sb += encl[t][e]*wfcW[50 + e]; }
    av[t] = sa; bv[t] = sb;
  }
  __syncthreads();
  if (t < 192){
    int i = t >> 4, sl = t & 15;
    float s = 0.f;
    for (int h = sl*32; h < sl*32 + 32; ++h){ float v = B0[i][h]; s += v*v; }
    part[i][sl] = s;
  }
  if (t == 192){
    float wbv = wfcB[0];
    float best = -1e30f; int bi = 0;
    for (int i = 0; i < 12; ++i){
      float rs = 0.f;
      for (int j = 0; j < 12; ++j) if (j != i) rs += av[i] + bv[j] + wbv;
      if (rs > best){ best = rs; bi = i; }
    }
    corei = bi;
  }
  __syncthreads();
  if (t < 12){
    float s = 0.f; for (int l = 0; l < 16; ++l) s += part[t][l];
    nrm[t] = sqrtf(s) + 1e-12f;
  }
  __syncthreads();
  if (t < 192){
    int i = t >> 4, sl = t & 15, cc = corei;
    float s = 0.f;
    for (int h = sl*32; h < sl*32 + 32; ++h) s += B0[i][h] * B0[cc][h];
    part[i][sl] = s;
  }
  __syncthreads();
  if (t < 12){
    float s = 0.f; for (int l = 0; l < 16; ++l) s += part[t][l];
    simv[t] = s / (nrm[t] * nrm[corei]);
  }
  __syncthreads();
  if (t < 12){
    int rk = 0; float st = simv[t];
    for (int j = 0; j < 12; ++j){
      float sj = simv[j];
      rk += (sj > st) || (sj == st && j < t);
    }
    rsv[t] = 1.f - (float)rk / 12.f;
  }
  __syncthreads();
  if (t < 144){
    int i = t / 12, j = t - (t / 12) * 12;
    Wm[i][j] = (i == j) ? 0.f : (av[i] + bv[j] + wfcB[0]) * rsv[i];
  }
  __syncthreads();
  for (int h = t; h < 512; h += 256){
    float e[12];
    #pragma unroll
    for (int j = 0; j < 12; ++j) e[j] = B0[j][h];
    #pragma unroll
    for (int i = 0; i < 12; ++i){
      float s = e[i];
      #pragma unroll
      for (int j = 0; j < 12; ++j) s += Wm[i][j] * e[j];
      B1[i][h] = s;
    }
  }
  __syncthreads();
  for (int h = t; h < 512; h += 256){
    float e[12];
    #pragma unroll
    for (int j = 0; j < 12; ++j) e[j] = B1[j][h];
    #pragma unroll
    for (int i = 0; i < 12; ++i){
      float s = e[i];
      #pragma unroll
      for (int j = 0; j < 12; ++j) s += Wm[i][j] * e[j];
      B0[i][h] = s;
    }
  }
  __syncthreads();
  if (t < 192){
    int i = t >> 4, sl = t & 15;
    float s = 0.f;
    for (int h = sl*32; h < sl*32 + 32; ++h) s += B0[i][h];
    part[i][sl] = s;
  }
  __syncthreads();
  if (t < 12){
    float s = 0.f; for (int l = 0; l < 16; ++l) s += part[t][l];
    docv[t] = s / 512.f;
  }
  __syncthreads();
  if (t < 2){
    float s = fcB[t];
    for (int i = 0; i < 12; ++i) s += docv[i] * fcW[t*12 + i];
    out[d*2 + t] = s;
  }
}

extern "C" void kernel_launch(void* const* d_in, const int* in_sizes, int n_in,
                              void* d_out, int out_size, void* d_ws, size_t ws_size,
                              hipStream_t stream){
  const float* x    = (const float*)d_in[0];
  const float* Wihf = (const float*)d_in[1];
  const float* Whhf = (const float*)d_in[2];
  const float* bihf = (const float*)d_in[3];
  const float* bhhf = (const float*)d_in[4];
  const float* Wihb = (const float*)d_in[5];
  const float* Whhb = (const float*)d_in[6];
  const float* bihb = (const float*)d_in[7];
  const float* bhhb = (const float*)d_in[8];
  const float* encW = (const float*)d_in[9];
  const float* encB = (const float*)d_in[10];
  const float* wfcW = (const float*)d_in[11];
  const float* wfcB = (const float*)d_in[12];
  const float* fcW  = (const float*)d_in[13];
  const float* fcB  = (const float*)d_in[14];
  float* out = (float*)d_out;
  char* ws = (char*)d_ws;
  _Float16* xh = (_Float16*)(ws);
  _Float16* wh = (_Float16*)(ws + 66453504);
  _Float16* G  = (_Float16*)(ws + 88604672);
  float* H = (float*)(ws);   // aliases dead xh after K1

  cvt_x<<<129792, 256, 0, stream>>>(x, xh);
  cvt_w<<<43264, 256, 0, stream>>>(Wihf, Wihb, wh);
  gemm_in<<<768, 256, 0, stream>>>(xh, wh, G, bihf, bhhf, bihb, bhhb);
  lstm_rec<<<24, 512, 0, stream>>>(Whhf, Whhb, G, H);
  epilogue<<<512, 256, 0, stream>>>(H, encW, encB, wfcW, wfcB, fcW, fcB, out);
}

// Round 4
// 1687.737 us; speedup vs baseline: 1.3502x; 1.0106x over previous
//
#include <hip/hip_runtime.h>
#include <hip/hip_bf16.h>
#include <hip/hip_fp16.h>

// BRNN: K0a/K0b fp32->fp16 convert+pad, K1 MFMA fp16 GEMM -> gate preacts G,
// K2 recurrence: 24 blocks (lane x dir) x 512 thr; thread (d=t>>2 dim-pair, q=t&3 K-chunk)
//   holds 8 gate-rows' K-chunk: i,f,g gates (6 rows, 192 u32) in VGPR, o gate (2 rows) in LDS.
//   amdgpu_waves_per_eu(2,2) pins the allocator to the 256-reg budget (launch_bounds alone
//   let the occupancy heuristic target 4 waves/EU and spill everything -> rounds 1-3).
//   h double-buffer padded to 36-dword chunk stride (bank offset 4q) -> no 4-way conflict.
// K3 per-doc epilogue.
// ws: [0,66453504) x_h (aliased by H after K1) | [66453504) W_h | [88604672) G. total 113,770,496 B.

typedef _Float16 h8 __attribute__((ext_vector_type(8)));
typedef _Float16 h2 __attribute__((ext_vector_type(2)));
typedef float f4 __attribute__((ext_vector_type(4)));

#define SEQ 512
#define NL 12
#define KIN 5400
#define KP 5408
#define NG 2048

__device__ __forceinline__ unsigned int pk2(float a, float b){
  h2 v; v[0] = (_Float16)a; v[1] = (_Float16)b;
  return __builtin_bit_cast(unsigned int, v);
}
__device__ __forceinline__ float dot2u(unsigned int h, unsigned int w, float acc){
  return __builtin_amdgcn_fdot2(__builtin_bit_cast(h2, h), __builtin_bit_cast(h2, w), acc, false);
}
__device__ __forceinline__ float dot4q(uint4 h, uint4 w, float acc){
  acc = dot2u(h.x, w.x, acc); acc = dot2u(h.y, w.y, acc);
  acc = dot2u(h.z, w.z, acc); acc = dot2u(h.w, w.w, acc);
  return acc;
}
__device__ __forceinline__ float sigm(float x){ return 1.f/(1.f + __expf(-x)); }
__device__ __forceinline__ float tanhx(float x){ return 1.f - 2.f/(__expf(2.f*x) + 1.f); }
__device__ __forceinline__ float dppadd_b1(float v){   // += lane^1
  int x = __builtin_amdgcn_mov_dpp(__builtin_bit_cast(int, v), 0xB1, 0xF, 0xF, true);
  return v + __builtin_bit_cast(float, x);
}
__device__ __forceinline__ float dppadd_4e(float v){   // += lane^2
  int x = __builtin_amdgcn_mov_dpp(__builtin_bit_cast(int, v), 0x4E, 0xF, 0xF, true);
  return v + __builtin_bit_cast(float, x);
}
__device__ __forceinline__ float lo16(unsigned int u){
  return (float)__builtin_bit_cast(h2, u)[0];
}
__device__ __forceinline__ float hi16(unsigned int u){
  return (float)__builtin_bit_cast(h2, u)[1];
}

// ---------------- K0a: x (6144x5400 f32) -> xh (6144x5408 f16, zero pad) ----------------
__global__ void cvt_x(const float* __restrict__ x, _Float16* __restrict__ xh){
  int idx = blockIdx.x * 256 + threadIdx.x;
  int row = idx / KP, col = idx - row * KP;
  float v = (col < KIN) ? x[(size_t)row * KIN + col] : 0.f;
  xh[idx] = (_Float16)v;
}

// ---------------- K0b: [Wih_f; Wih_b] -> wh (2048x5408 f16, zero pad) ----------------
__global__ void cvt_w(const float* __restrict__ wf, const float* __restrict__ wb,
                      _Float16* __restrict__ wh){
  int idx = blockIdx.x * 256 + threadIdx.x;
  int row = idx / KP, col = idx - row * KP;
  float v = 0.f;
  if (col < KIN)
    v = (row < 1024) ? wf[(size_t)row * KIN + col] : wb[(size_t)(row - 1024) * KIN + col];
  wh[idx] = (_Float16)v;
}

// ---------------- K1: G = xh @ wh^T + bias, fp16 MFMA, 128x128 tiles ----------------
__global__ __launch_bounds__(256) void gemm_in(
    const _Float16* __restrict__ A, const _Float16* __restrict__ B, _Float16* __restrict__ G,
    const float* __restrict__ bif, const float* __restrict__ bhf,
    const float* __restrict__ bib, const float* __restrict__ bhb){
  __shared__ _Float16 As[128 * 40];
  __shared__ _Float16 Bs[128 * 40];
  int tid = threadIdx.x;
  int bm = blockIdx.x % 48, bn = blockIdx.x / 48;
  int wid = tid >> 6, ln = tid & 63;
  int wm = wid & 1, wn = wid >> 1;
  int l15 = ln & 15, q = ln >> 4;
  int i0 = tid, i1 = tid + 256;
  int r0 = i0 >> 2, c0 = i0 & 3, r1 = i1 >> 2, c1 = i1 & 3;
  const size_t a0 = (size_t)(bm*128 + r0) * KP + c0*8;
  const size_t a1 = (size_t)(bm*128 + r1) * KP + c1*8;
  const size_t b0 = (size_t)(bn*128 + r0) * KP + c0*8;
  const size_t b1 = (size_t)(bn*128 + r1) * KP + c1*8;
  f4 acc[4][4] = {};
  for (int kk = 0; kk < 169; ++kk){
    int k0 = kk * 32;
    uint4 va0 = *(const uint4*)(A + a0 + k0);
    uint4 va1 = *(const uint4*)(A + a1 + k0);
    uint4 vb0 = *(const uint4*)(B + b0 + k0);
    uint4 vb1 = *(const uint4*)(B + b1 + k0);
    __syncthreads();
    *(uint4*)(As + r0*40 + c0*8) = va0;
    *(uint4*)(As + r1*40 + c1*8) = va1;
    *(uint4*)(Bs + r0*40 + c0*8) = vb0;
    *(uint4*)(Bs + r1*40 + c1*8) = vb1;
    __syncthreads();
    h8 af[4], bfr[4];
    #pragma unroll
    for (int mt = 0; mt < 4; ++mt)
      af[mt] = *(const h8*)(As + (wm*64 + mt*16 + l15)*40 + q*8);
    #pragma unroll
    for (int nt = 0; nt < 4; ++nt)
      bfr[nt] = *(const h8*)(Bs + (wn*64 + nt*16 + l15)*40 + q*8);
    #pragma unroll
    for (int mt = 0; mt < 4; ++mt)
      #pragma unroll
      for (int nt = 0; nt < 4; ++nt)
        acc[mt][nt] = __builtin_amdgcn_mfma_f32_16x16x32_f16(af[mt], bfr[nt], acc[mt][nt], 0, 0, 0);
  }
  float bias[4];
  #pragma unroll
  for (int nt = 0; nt < 4; ++nt){
    int col = bn*128 + wn*64 + nt*16 + l15;
    bias[nt] = (col < 1024) ? (bif[col] + bhf[col]) : (bib[col-1024] + bhb[col-1024]);
  }
  #pragma unroll
  for (int mt = 0; mt < 4; ++mt)
    #pragma unroll
    for (int nt = 0; nt < 4; ++nt)
      #pragma unroll
      for (int r = 0; r < 4; ++r){
        int row = bm*128 + wm*64 + mt*16 + q*4 + r;
        int col = bn*128 + wn*64 + nt*16 + l15;
        G[(size_t)row * NG + col] = (_Float16)(acc[mt][nt][r] + bias[nt]);
      }
}

// ---------------- K2: recurrence, hybrid VGPR+LDS weights, pinned 2 waves/EU ----------------
__global__ void __attribute__((amdgpu_flat_work_group_size(512, 512), amdgpu_waves_per_eu(2, 2)))
lstm_rec(
    const float* __restrict__ Whhf, const float* __restrict__ Whhb,
    const _Float16* __restrict__ G, float* __restrict__ Hout){
  __shared__ uint4 wl[2][8][512];          // 131072 B, o-gate weights
  __shared__ unsigned int hbp[2][4][36];   // h double-buffer, 36-dword chunk stride
  int b = blockIdx.x;
  int dir = b / 12, lane = b - dir * 12;
  int t = threadIdx.x;
  int d = t >> 2, q = t & 3;
  const float* Whh = dir ? Whhb : Whhf;

  // VGPR rows: gates i,f,g (g in {0,1,2}) x dims {2d, 2d+1}.
  uint4 wreg[6][8];
  #pragma unroll
  for (int g = 0; g < 3; ++g)
    #pragma unroll
    for (int dd = 0; dd < 2; ++dd){
      const float* wr = Whh + (size_t)(g*256 + 2*d + dd) * 256 + q*64;
      #pragma unroll
      for (int c = 0; c < 8; ++c){
        f4 v0 = *(const f4*)(wr + c*8);
        f4 v1 = *(const f4*)(wr + c*8 + 4);
        uint4 u;
        u.x = pk2(v0[0], v0[1]); u.y = pk2(v0[2], v0[3]);
        u.z = pk2(v1[0], v1[1]); u.w = pk2(v1[2], v1[3]);
        wreg[g*2 + dd][c] = u;
      }
    }
  // LDS rows: o gate (rows 768 + 2d + dd)
  #pragma unroll
  for (int dd = 0; dd < 2; ++dd){
    const float* wr = Whh + (size_t)(768 + 2*d + dd) * 256 + q*64;
    #pragma unroll
    for (int c = 0; c < 8; ++c){
      f4 v0 = *(const f4*)(wr + c*8);
      f4 v1 = *(const f4*)(wr + c*8 + 4);
      uint4 u;
      u.x = pk2(v0[0], v0[1]); u.y = pk2(v0[2], v0[3]);
      u.z = pk2(v1[0], v1[1]); u.w = pk2(v1[2], v1[3]);
      wl[dd][c][t] = u;
    }
  }
  if (t < 288) ((unsigned int*)hbp)[t] = 0u;

  int s0 = dir ? (SEQ - 1) : 0;
  long sstep = dir ? -(long)(NL*NG/2) : (long)(NL*NG/2);       // u32 units
  long hstep = dir ? -(long)(NL*512/2) : (long)(NL*512/2);     // float2 units
  const unsigned int* gp = (const unsigned int*)(G + (size_t)(s0*NL + lane) * NG + dir * 1024) + d;
  float2* hp = (float2*)(Hout + (size_t)(s0*NL + lane) * 512 + dir * 256) + d;
  float c0 = 0.f, c1 = 0.f;
  __syncthreads();

  for (int it = 0; it < SEQ; ++it){
    unsigned int gi = gp[0];
    unsigned int gf = gp[128];
    unsigned int gg = gp[256];
    unsigned int go = gp[384];
    const uint4* hq = (const uint4*)&hbp[it & 1][q][0];
    float a0=0.f,a1=0.f,a2=0.f,a3=0.f,a4=0.f,a5=0.f,a6=0.f,a7=0.f;
    #pragma unroll
    for (int c = 0; c < 8; ++c){
      uint4 hv = hq[c];
      uint4 w6 = wl[0][c][t];
      uint4 w7 = wl[1][c][t];
      a0 = dot4q(hv, wreg[0][c], a0);
      a1 = dot4q(hv, wreg[1][c], a1);
      a2 = dot4q(hv, wreg[2][c], a2);
      a3 = dot4q(hv, wreg[3][c], a3);
      a4 = dot4q(hv, wreg[4][c], a4);
      a5 = dot4q(hv, wreg[5][c], a5);
      a6 = dot4q(hv, w6, a6);
      a7 = dot4q(hv, w7, a7);
    }
    a0 = dppadd_4e(dppadd_b1(a0));
    a1 = dppadd_4e(dppadd_b1(a1));
    a2 = dppadd_4e(dppadd_b1(a2));
    a3 = dppadd_4e(dppadd_b1(a3));
    a4 = dppadd_4e(dppadd_b1(a4));
    a5 = dppadd_4e(dppadd_b1(a5));
    a6 = dppadd_4e(dppadd_b1(a6));
    a7 = dppadd_4e(dppadd_b1(a7));
    float pi0 = a0 + lo16(gi), pi1 = a1 + hi16(gi);
    float pf0 = a2 + lo16(gf), pf1 = a3 + hi16(gf);
    float pg0 = a4 + lo16(gg), pg1 = a5 + hi16(gg);
    float po0 = a6 + lo16(go), po1 = a7 + hi16(go);
    c0 = sigm(pf0)*c0 + sigm(pi0)*tanhx(pg0);
    c1 = sigm(pf1)*c1 + sigm(pi1)*tanhx(pg1);
    float h0 = sigm(po0)*tanhx(c0);
    float h1 = sigm(po1)*tanhx(c1);
    if (q == 0){
      hbp[(it & 1) ^ 1][d >> 5][d & 31] = pk2(h0, h1);
      float2 hw; hw.x = h0; hw.y = h1;
      *hp = hw;
    }
    gp += sstep; hp += hstep;
    __syncthreads();
  }
}

// ---------------- K3: per-doc epilogue ----------------
__global__ __launch_bounds__(256) void epilogue(
    const float* __restrict__ H, const float* __restrict__ encW, const float* __restrict__ encB,
    const float* __restrict__ wfcW, const float* __restrict__ wfcB,
    const float* __restrict__ fcW, const float* __restrict__ fcB, float* __restrict__ out){
  __shared__ float B0[12][516];
  __shared__ float B1[12][516];
  __shared__ float encl[12][52];
  __shared__ float part[12][16];
  __shared__ float av[12], bv[12], nrm[12], simv[12], rsv[12], docv[12];
  __shared__ float Wm[12][12];
  __shared__ int corei;
  int d = blockIdx.x, t = threadIdx.x;
  const float* Hd = H + (size_t)d * NL * 512;
  for (int idx = t; idx < NL * 128; idx += 256){
    int i = idx >> 7, h4 = (idx & 127) * 4;
    *(f4*)(&B0[i][h4]) = *(const f4*)(Hd + i*512 + h4);
  }
  __syncthreads();
  for (int idx = t; idx < 600; idx += 256){
    int i = idx % 12, e = idx / 12;
    float s = encB[e];
    const float* w = encW + e * 512;
    for (int h = 0; h < 512; ++h) s += B0[i][h] * w[h];
    encl[i][e] = (s >= 0.f) ? s : 0.01f * s;
  }
  __syncthreads();
  if (t < 12){
    float sa = 0.f, sb = 0.f;
    for (int e = 0; e < 50; ++e){ sa += encl[t][e]*wfcW[e]; sb += encl[t][e]*wfcW[50 + e]; }
    av[t] = sa; bv[t] = sb;
  }
  __syncthreads();
  if (t < 192){
    int i = t >> 4, sl = t & 15;
    float s = 0.f;
    for (int h = sl*32; h < sl*32 + 32; ++h){ float v = B0[i][h]; s += v*v; }
    part[i][sl] = s;
  }
  if (t == 192){
    float wbv = wfcB[0];
    float best = -1e30f; int bi = 0;
    for (int i = 0; i < 12; ++i){
      float rs = 0.f;
      for (int j = 0; j < 12; ++j) if (j != i) rs += av[i] + bv[j] + wbv;
      if (rs > best){ best = rs; bi = i; }
    }
    corei = bi;
  }
  __syncthreads();
  if (t < 12){
    float s = 0.f; for (int l = 0; l < 16; ++l) s += part[t][l];
    nrm[t] = sqrtf(s) + 1e-12f;
  }
  __syncthreads();
  if (t < 192){
    int i = t >> 4, sl = t & 15, cc = corei;
    float s = 0.f;
    for (int h = sl*32; h < sl*32 + 32; ++h) s += B0[i][h] * B0[cc][h];
    part[i][sl] = s;
  }
  __syncthreads();
  if (t < 12){
    float s = 0.f; for (int l = 0; l < 16; ++l) s += part[t][l];
    simv[t] = s / (nrm[t] * nrm[corei]);
  }
  __syncthreads();
  if (t < 12){
    int rk = 0; float st = simv[t];
    for (int j = 0; j < 12; ++j){
      float sj = simv[j];
      rk += (sj > st) || (sj == st && j < t);
    }
    rsv[t] = 1.f - (float)rk / 12.f;
  }
  __syncthreads();
  if (t < 144){
    int i = t / 12, j = t - (t / 12) * 12;
    Wm[i][j] = (i == j) ? 0.f : (av[i] + bv[j] + wfcB[0]) * rsv[i];
  }
  __syncthreads();
  for (int h = t; h < 512; h += 256){
    float e[12];
    #pragma unroll
    for (int j = 0; j < 12; ++j) e[j] = B0[j][h];
    #pragma unroll
    for (int i = 0; i < 12; ++i){
      float s = e[i];
      #pragma unroll
      for (int j = 0; j < 12; ++j) s += Wm[i][j] * e[j];
      B1[i][h] = s;
    }
  }
  __syncthreads();
  for (int h = t; h < 512; h += 256){
    float e[12];
    #pragma unroll
    for (int j = 0; j < 12; ++j) e[j] = B1[j][h];
    #pragma unroll
    for (int i = 0; i < 12; ++i){
      float s = e[i];
      #pragma unroll
      for (int j = 0; j < 12; ++j) s += Wm[i][j] * e[j];
      B0[i][h] = s;
    }
  }
  __syncthreads();
  if (t < 192){
    int i = t >> 4, sl = t & 15;
    float s = 0.f;
    for (int h = sl*32; h < sl*32 + 32; ++h) s += B0[i][h];
    part[i][sl] = s;
  }
  __syncthreads();
  if (t < 12){
    float s = 0.f; for (int l = 0; l < 16; ++l) s += part[t][l];
    docv[t] = s / 512.f;
  }
  __syncthreads();
  if (t < 2){
    float s = fcB[t];
    for (int i = 0; i < 12; ++i) s += docv[i] * fcW[t*12 + i];
    out[d*2 + t] = s;
  }
}

extern "C" void kernel_launch(void* const* d_in, const int* in_sizes, int n_in,
                              void* d_out, int out_size, void* d_ws, size_t ws_size,
                              hipStream_t stream){
  const float* x    = (const float*)d_in[0];
  const float* Wihf = (const float*)d_in[1];
  const float* Whhf = (const float*)d_in[2];
  const float* bihf = (const float*)d_in[3];
  const float* bhhf = (const float*)d_in[4];
  const float* Wihb = (const float*)d_in[5];
  const float* Whhb = (const float*)d_in[6];
  const float* bihb = (const float*)d_in[7];
  const float* bhhb = (const float*)d_in[8];
  const float* encW = (const float*)d_in[9];
  const float* encB = (const float*)d_in[10];
  const float* wfcW = (const float*)d_in[11];
  const float* wfcB = (const float*)d_in[12];
  const float* fcW  = (const float*)d_in[13];
  const float* fcB  = (const float*)d_in[14];
  float* out = (float*)d_out;
  char* ws = (char*)d_ws;
  _Float16* xh = (_Float16*)(ws);
  _Float16* wh = (_Float16*)(ws + 66453504);
  _Float16* G  = (_Float16*)(ws + 88604672);
  float* H = (float*)(ws);   // aliases dead xh after K1

  cvt_x<<<129792, 256, 0, stream>>>(x, xh);
  cvt_w<<<43264, 256, 0, stream>>>(Wihf, Wihb, wh);
  gemm_in<<<768, 256, 0, stream>>>(xh, wh, G, bihf, bhhf, bihb, bhhb);
  lstm_rec<<<24, 512, 0, stream>>>(Whhf, Whhb, G, H);
  epilogue<<<512, 256, 0, stream>>>(H, encW, encB, wfcW, wfcB, fcW, fcB, out);
}